// Round 1
// baseline (169.801 us; speedup 1.0000x reference)
//
#include <hip/hip_runtime.h>
#include <hip/hip_bf16.h>
#include <stdint.h>

#define EMBED 1024
#define HEADS 16
#define HDIM 64
#define BATCH 2
#define SEQ 2048
#define NROWS (BATCH*SEQ)

typedef __attribute__((ext_vector_type(8))) short short8;
typedef __attribute__((ext_vector_type(4))) float f32x4;

#define LOG2E 1.44269504088896f

__device__ __forceinline__ unsigned short f2bf(float f) {
    __hip_bfloat16 b = __float2bfloat16(f);
    return *reinterpret_cast<unsigned short*>(&b);
}

__device__ __forceinline__ void g2l16(const void* g, void* l) {
    __builtin_amdgcn_global_load_lds(
        (const __attribute__((address_space(1))) unsigned int*)g,
        (__attribute__((address_space(3))) unsigned int*)l, 16, 0, 0);
}

// ---------------- cast x (fp32 -> bf16), vectorized ----------------
__global__ void cast_x_kernel(const float* __restrict__ x,
                              unsigned short* __restrict__ xb, int n4) {
    int i = blockIdx.x * blockDim.x + threadIdx.x;
    if (i < n4) {
        float4 v = reinterpret_cast<const float4*>(x)[i];
        ushort4 o;
        o.x = f2bf(v.x); o.y = f2bf(v.y); o.z = f2bf(v.z); o.w = f2bf(v.w);
        reinterpret_cast<ushort4*>(xb)[i] = o;
    }
}

// ---------------- transpose + cast W [in][out] fp32 -> Wt [out][in] bf16 ----
__global__ void transW_kernel(const float* __restrict__ W,
                              unsigned short* __restrict__ Wt) {
    __shared__ float tile[32][33];
    int tx = threadIdx.x, ty = threadIdx.y;
#pragma unroll
    for (int r = 0; r < 4; r++) {
        int i = blockIdx.y * 32 + ty + r * 8;
        int o = blockIdx.x * 32 + tx;
        tile[ty + r * 8][tx] = W[(size_t)i * EMBED + o];
    }
    __syncthreads();
    int i2 = blockIdx.y * 32 + tx;
#pragma unroll
    for (int r = 0; r < 4; r++) {
        int o2 = blockIdx.x * 32 + ty + r * 8;
        Wt[(size_t)o2 * EMBED + i2] = f2bf(tile[tx][ty + r * 8]);
    }
}

// ---------------- GEMM: C[M][N] = A[M][K] * B[N][K]^T  (bf16 in, fp32 acc) --
// MODE 0: N=3072 fused QKV; epilogue scatters to Q[b,h,s,d] (scaled 1/8),
//         K[b,h,s,d], V^T[b,h,d,s] with bias.
// MODE 1: attn-out projection; epilogue writes fp32 out + bias.
template<int MODE>
__global__ __launch_bounds__(256)
void gemm_kernel(const unsigned short* __restrict__ A,
                 const unsigned short* __restrict__ B,
                 int K,
                 unsigned short* __restrict__ Qo,
                 unsigned short* __restrict__ Ko,
                 unsigned short* __restrict__ Vto,
                 const float* __restrict__ bq,
                 const float* __restrict__ bk,
                 const float* __restrict__ bvv,
                 float* __restrict__ Co,
                 const float* __restrict__ bo) {
    __shared__ __attribute__((aligned(16))) unsigned short As[128 * 64];
    __shared__ __attribute__((aligned(16))) unsigned short Bs[128 * 64];
    const int t = threadIdx.x;
    const int lane = t & 63;
    const int w = t >> 6;
    const int wr = w >> 1, wc = w & 1;
    const int l15 = lane & 15, l16 = lane >> 4;
    const int m0 = blockIdx.y * 128;
    const int n0 = blockIdx.x * 128;

    f32x4 acc[4][4];
#pragma unroll
    for (int i = 0; i < 4; i++)
#pragma unroll
        for (int j = 0; j < 4; j++) acc[i][j] = (f32x4){0.f, 0.f, 0.f, 0.f};

    for (int k0 = 0; k0 < K; k0 += 64) {
        __syncthreads();
#pragma unroll
        for (int i = 0; i < 4; i++) {   // stage A tile [128][64], swizzled source
            int c = i * 256 + t;
            int row = c >> 3;
            int lc = (c & 7) ^ (row & 7);
            g2l16(A + (size_t)(m0 + row) * K + k0 + lc * 8,
                  As + (size_t)(i * 256 + (t & ~63)) * 8);
        }
#pragma unroll
        for (int i = 0; i < 4; i++) {   // stage B tile [128][64]
            int c = i * 256 + t;
            int row = c >> 3;
            int lc = (c & 7) ^ (row & 7);
            g2l16(B + (size_t)(n0 + row) * K + k0 + lc * 8,
                  Bs + (size_t)(i * 256 + (t & ~63)) * 8);
        }
        __syncthreads();
#pragma unroll
        for (int kk = 0; kk < 2; kk++) {
            short8 a[4], b[4];
#pragma unroll
            for (int ai = 0; ai < 4; ai++) {
                int row = wr * 64 + ai * 16 + l15;
                int ch = kk * 4 + l16;
                a[ai] = *reinterpret_cast<const short8*>(
                    As + row * 64 + ((ch ^ (row & 7)) << 3));
            }
#pragma unroll
            for (int bj = 0; bj < 4; bj++) {
                int row = wc * 64 + bj * 16 + l15;
                int ch = kk * 4 + l16;
                b[bj] = *reinterpret_cast<const short8*>(
                    Bs + row * 64 + ((ch ^ (row & 7)) << 3));
            }
#pragma unroll
            for (int ai = 0; ai < 4; ai++)
#pragma unroll
                for (int bj = 0; bj < 4; bj++)
                    acc[ai][bj] = __builtin_amdgcn_mfma_f32_16x16x32_bf16(
                        a[ai], b[bj], acc[ai][bj], 0, 0, 0);
        }
    }

    if (MODE == 0) {
        const int which = n0 >> 10;        // 0=Q 1=K 2=V
        const int coln = n0 & 1023;
        const float* bias = which == 0 ? bq : (which == 1 ? bk : bvv);
        const float scale = which == 0 ? 0.125f : 1.0f;
#pragma unroll
        for (int ai = 0; ai < 4; ai++) {
            int rowb = m0 + wr * 64 + ai * 16 + l16 * 4;
            int b_ = rowb >> 11;
            int s = rowb & 2047;
#pragma unroll
            for (int bj = 0; bj < 4; bj++) {
                int col = coln + wc * 64 + bj * 16 + l15;
                float bsv = bias[col];
                int h = col >> 6, d = col & 63;
                if (which < 2) {
                    unsigned short* dst = (which == 0) ? Qo : Ko;
                    size_t base = ((size_t)(b_ * HEADS + h)) * SEQ * HDIM;
#pragma unroll
                    for (int r = 0; r < 4; r++) {
                        float v = (acc[ai][bj][r] + bsv) * scale;
                        dst[base + (size_t)(s + r) * HDIM + d] = f2bf(v);
                    }
                } else {
                    ushort4 pk;
                    pk.x = f2bf(acc[ai][bj][0] + bsv);
                    pk.y = f2bf(acc[ai][bj][1] + bsv);
                    pk.z = f2bf(acc[ai][bj][2] + bsv);
                    pk.w = f2bf(acc[ai][bj][3] + bsv);
                    size_t off = ((size_t)(b_ * HEADS + h) * HDIM + d) * SEQ + s;
                    *reinterpret_cast<ushort4*>(Vto + off) = pk;
                }
            }
        }
    } else {
#pragma unroll
        for (int ai = 0; ai < 4; ai++) {
            int rowb = m0 + wr * 64 + ai * 16 + l16 * 4;
#pragma unroll
            for (int bj = 0; bj < 4; bj++) {
                int col = n0 + wc * 64 + bj * 16 + l15;
                float bsv = bo[col];
#pragma unroll
                for (int r = 0; r < 4; r++)
                    Co[(size_t)(rowb + r) * EMBED + col] = acc[ai][bj][r] + bsv;
            }
        }
    }
}

// ---------------- causal flash attention -----------------------------------
// Q,K: [bh][s][64] bf16 (Q pre-scaled by 1/8); V: [bh][64][s] bf16 (transposed)
// O: [b*s][1024] bf16.  Block: 4 waves x 32 q-rows = 128 q-rows; KV tile 64.
__global__ __launch_bounds__(256)
void attn_kernel(const unsigned short* __restrict__ Q,
                 const unsigned short* __restrict__ Kk,
                 const unsigned short* __restrict__ Vt,
                 unsigned short* __restrict__ O) {
    __shared__ __attribute__((aligned(16))) unsigned short Qs[128 * 64];
    __shared__ __attribute__((aligned(16))) unsigned short Ks[64 * 64];
    __shared__ __attribute__((aligned(16))) unsigned short Vs[64 * 64];
    __shared__ __attribute__((aligned(16))) unsigned short Ps[4][32 * 64];

    const int t = threadIdx.x;
    const int lane = t & 63;
    const int w = t >> 6;
    const int l15 = lane & 15, l16 = lane >> 4;
    const int bh = blockIdx.y;
    const int q0 = blockIdx.x * 128;
    const size_t base = (size_t)bh * SEQ * HDIM;

    {   // stage Q tile [128][64] (contiguous 16 KB), swizzled source
        const unsigned short* src = Q + base + (size_t)q0 * HDIM;
#pragma unroll
        for (int i = 0; i < 4; i++) {
            int c = i * 256 + t;
            int row = c >> 3;
            int lc = (c & 7) ^ (row & 7);
            g2l16(src + row * 64 + lc * 8, Qs + (i * 256 + (t & ~63)) * 8);
        }
    }
    __syncthreads();
    short8 qf[2][2];
#pragma unroll
    for (int mi = 0; mi < 2; mi++)
#pragma unroll
        for (int kc = 0; kc < 2; kc++) {
            int row = w * 32 + mi * 16 + l15;
            int ch = kc * 4 + l16;
            qf[mi][kc] = *reinterpret_cast<const short8*>(
                Qs + row * 64 + ((ch ^ (row & 7)) << 3));
        }

    f32x4 oacc[2][4];
    float m_run[2][4], l_run[2][4];
#pragma unroll
    for (int mi = 0; mi < 2; mi++) {
#pragma unroll
        for (int n = 0; n < 4; n++) oacc[mi][n] = (f32x4){0.f, 0.f, 0.f, 0.f};
#pragma unroll
        for (int r = 0; r < 4; r++) { m_run[mi][r] = -1e30f; l_run[mi][r] = 0.f; }
    }

    const int qminw = q0 + w * 32;
    const int qmaxw = qminw + 31;
    const int ntiles = (q0 >> 6) + 2;

    for (int tk = 0; tk < ntiles; tk++) {
        const int kv0 = tk * 64;
        __syncthreads();
        {   // stage K tile [64][64] (contiguous 8 KB)
            const unsigned short* srck = Kk + base + (size_t)kv0 * HDIM;
#pragma unroll
            for (int i = 0; i < 2; i++) {
                int c = i * 256 + t;
                int row = c >> 3;
                int lc = (c & 7) ^ (row & 7);
                g2l16(srck + row * 64 + lc * 8, Ks + (i * 256 + (t & ~63)) * 8);
            }
            // stage V^T tile [64 d][64 s]
            const unsigned short* srcv = Vt + base;
#pragma unroll
            for (int i = 0; i < 2; i++) {
                int c = i * 256 + t;
                int d = c >> 3;
                int lc = (c & 7) ^ (d & 7);
                g2l16(srcv + (size_t)d * SEQ + kv0 + lc * 8,
                      Vs + (i * 256 + (t & ~63)) * 8);
            }
        }
        __syncthreads();
        if (kv0 > qmaxw) continue;   // barriers already passed; wave-uniform

        // ---- QK^T: sc[mi][n] over 32 q-rows x 64 keys
        f32x4 sc[2][4];
#pragma unroll
        for (int mi = 0; mi < 2; mi++)
#pragma unroll
            for (int n = 0; n < 4; n++) sc[mi][n] = (f32x4){0.f, 0.f, 0.f, 0.f};
#pragma unroll
        for (int kc = 0; kc < 2; kc++) {
            short8 kb[4];
#pragma unroll
            for (int n = 0; n < 4; n++) {
                int row = n * 16 + l15;
                int ch = kc * 4 + l16;
                kb[n] = *reinterpret_cast<const short8*>(
                    Ks + row * 64 + ((ch ^ (row & 7)) << 3));
            }
#pragma unroll
            for (int mi = 0; mi < 2; mi++)
#pragma unroll
                for (int n = 0; n < 4; n++)
                    sc[mi][n] = __builtin_amdgcn_mfma_f32_16x16x32_bf16(
                        qf[mi][kc], kb[n], sc[mi][n], 0, 0, 0);
        }
        // ---- causal mask (only needed on diagonal tiles)
        if (kv0 + 63 > qminw) {
#pragma unroll
            for (int mi = 0; mi < 2; mi++)
#pragma unroll
                for (int n = 0; n < 4; n++)
#pragma unroll
                    for (int r = 0; r < 4; r++) {
                        int q = qminw + mi * 16 + l16 * 4 + r;
                        int k = kv0 + n * 16 + l15;
                        sc[mi][n][r] = (k > q) ? -1e30f : sc[mi][n][r];
                    }
        }
        // ---- online softmax update
#pragma unroll
        for (int mi = 0; mi < 2; mi++) {
#pragma unroll
            for (int r = 0; r < 4; r++) {
                float v = fmaxf(fmaxf(sc[mi][0][r], sc[mi][1][r]),
                                fmaxf(sc[mi][2][r], sc[mi][3][r]));
                v = fmaxf(v, __shfl_xor(v, 1));
                v = fmaxf(v, __shfl_xor(v, 2));
                v = fmaxf(v, __shfl_xor(v, 4));
                v = fmaxf(v, __shfl_xor(v, 8));
                float mn = fmaxf(m_run[mi][r], v);
                float sf = __builtin_amdgcn_exp2f((m_run[mi][r] - mn) * LOG2E);
                m_run[mi][r] = mn;
                l_run[mi][r] *= sf;
#pragma unroll
                for (int n = 0; n < 4; n++) oacc[mi][n][r] *= sf;
                float rs = 0.f;
                int row = mi * 16 + l16 * 4 + r;
#pragma unroll
                for (int n = 0; n < 4; n++) {
                    float p = __builtin_amdgcn_exp2f((sc[mi][n][r] - mn) * LOG2E);
                    rs += p;
                    int col = n * 16 + l15;
                    Ps[w][row * 64 + (((col >> 3) ^ (row & 7)) << 3) + (col & 7)] =
                        f2bf(p);
                }
                l_run[mi][r] += rs;
            }
        }
        // ---- PV: oacc += P[32 x 64keys] * V[64keys x 64d]
#pragma unroll
        for (int kc = 0; kc < 2; kc++) {
            short8 pa[2], vb[4];
#pragma unroll
            for (int mi = 0; mi < 2; mi++) {
                int row = mi * 16 + l15;
                int ch = kc * 4 + l16;
                pa[mi] = *reinterpret_cast<const short8*>(
                    &Ps[w][row * 64 + ((ch ^ (row & 7)) << 3)]);
            }
#pragma unroll
            for (int nd = 0; nd < 4; nd++) {
                int row = nd * 16 + l15;
                int ch = kc * 4 + l16;
                vb[nd] = *reinterpret_cast<const short8*>(
                    Vs + row * 64 + ((ch ^ (row & 7)) << 3));
            }
#pragma unroll
            for (int mi = 0; mi < 2; mi++)
#pragma unroll
                for (int nd = 0; nd < 4; nd++)
                    oacc[mi][nd] = __builtin_amdgcn_mfma_f32_16x16x32_bf16(
                        pa[mi], vb[nd], oacc[mi][nd], 0, 0, 0);
        }
    }

    // ---- finalize: reduce row-sum across the 16-lane group, normalize, store
    const int b_ = bh >> 4, h = bh & 15;
#pragma unroll
    for (int mi = 0; mi < 2; mi++) {
#pragma unroll
        for (int r = 0; r < 4; r++) {
            float l = l_run[mi][r];
            l += __shfl_xor(l, 1);
            l += __shfl_xor(l, 2);
            l += __shfl_xor(l, 4);
            l += __shfl_xor(l, 8);
            float inv = 1.0f / l;
            int row = b_ * SEQ + q0 + w * 32 + mi * 16 + l16 * 4 + r;
#pragma unroll
            for (int nd = 0; nd < 4; nd++)
                O[(size_t)row * EMBED + h * 64 + nd * 16 + l15] =
                    f2bf(oacc[mi][nd][r] * inv);
        }
    }
}

extern "C" void kernel_launch(void* const* d_in, const int* in_sizes, int n_in,
                              void* d_out, int out_size, void* d_ws, size_t ws_size,
                              hipStream_t stream) {
    (void)in_sizes; (void)n_in; (void)out_size; (void)ws_size;
    const float* x  = (const float*)d_in[0];
    const float* Wq = (const float*)d_in[1];
    const float* bq = (const float*)d_in[2];
    const float* Wk = (const float*)d_in[3];
    const float* bk = (const float*)d_in[4];
    const float* Wv = (const float*)d_in[5];
    const float* bv = (const float*)d_in[6];
    const float* Wo = (const float*)d_in[7];
    const float* bo = (const float*)d_in[8];
    float* out = (float*)d_out;

    // workspace layout (bf16 elements), total 48 MB
    unsigned short* xb   = (unsigned short*)d_ws;
    unsigned short* Wqkv = xb + (size_t)NROWS * EMBED;          // [3][1024][1024]
    unsigned short* Wot  = Wqkv + (size_t)3 * EMBED * EMBED;
    unsigned short* Qb   = Wot + (size_t)EMBED * EMBED;         // [b,h,s,d]
    unsigned short* Kb   = Qb + (size_t)NROWS * EMBED;
    unsigned short* Vtb  = Kb + (size_t)NROWS * EMBED;          // [b,h,d,s]
    unsigned short* attn = Vtb + (size_t)NROWS * EMBED;         // [b*s][1024]

    cast_x_kernel<<<(NROWS * EMBED / 4 + 255) / 256, 256, 0, stream>>>(
        x, xb, NROWS * EMBED / 4);
    dim3 tgrid(32, 32), tblk(32, 8);
    transW_kernel<<<tgrid, tblk, 0, stream>>>(Wq, Wqkv);
    transW_kernel<<<tgrid, tblk, 0, stream>>>(Wk, Wqkv + (size_t)EMBED * EMBED);
    transW_kernel<<<tgrid, tblk, 0, stream>>>(Wv, Wqkv + (size_t)2 * EMBED * EMBED);
    transW_kernel<<<tgrid, tblk, 0, stream>>>(Wo, Wot);

    gemm_kernel<0><<<dim3(24, 32), 256, 0, stream>>>(
        xb, Wqkv, EMBED, Qb, Kb, Vtb, bq, bk, bv, nullptr, nullptr);

    attn_kernel<<<dim3(SEQ / 128, BATCH * HEADS), 256, 0, stream>>>(
        Qb, Kb, Vtb, attn);

    gemm_kernel<1><<<dim3(8, 32), 256, 0, stream>>>(
        attn, Wot, EMBED, nullptr, nullptr, nullptr, nullptr, nullptr, nullptr,
        out, bo);
}

// Round 2
// 138.189 us; speedup vs baseline: 1.2288x; 1.2288x over previous
//
#include <hip/hip_runtime.h>
#include <hip/hip_bf16.h>
#include <stdint.h>

#define EMBED 1024
#define HEADS 16
#define HDIM 64
#define BATCH 2
#define SEQ 2048
#define NROWS (BATCH*SEQ)

typedef __attribute__((ext_vector_type(8))) short short8;
typedef __attribute__((ext_vector_type(4))) float f32x4;

#define LOG2E 1.44269504088896f

__device__ __forceinline__ unsigned short f2bf(float f) {
    __hip_bfloat16 b = __float2bfloat16(f);
    return *reinterpret_cast<unsigned short*>(&b);
}

__device__ __forceinline__ void g2l16(const void* g, void* l) {
    __builtin_amdgcn_global_load_lds(
        (const __attribute__((address_space(1))) unsigned int*)g,
        (__attribute__((address_space(3))) unsigned int*)l, 16, 0, 0);
}

// ---------------- cast x (fp32 -> bf16), vectorized ----------------
__global__ void cast_x_kernel(const float* __restrict__ x,
                              unsigned short* __restrict__ xb, int n4) {
    int i = blockIdx.x * blockDim.x + threadIdx.x;
    if (i < n4) {
        float4 v = reinterpret_cast<const float4*>(x)[i];
        ushort4 o;
        o.x = f2bf(v.x); o.y = f2bf(v.y); o.z = f2bf(v.z); o.w = f2bf(v.w);
        reinterpret_cast<ushort4*>(xb)[i] = o;
    }
}

// ---------------- transpose + cast W [in][out] fp32 -> Wt [out][in] bf16 ----
__global__ void transW_kernel(const float* __restrict__ W,
                              unsigned short* __restrict__ Wt) {
    __shared__ float tile[32][33];
    int tx = threadIdx.x, ty = threadIdx.y;
#pragma unroll
    for (int r = 0; r < 4; r++) {
        int i = blockIdx.y * 32 + ty + r * 8;
        int o = blockIdx.x * 32 + tx;
        tile[ty + r * 8][tx] = W[(size_t)i * EMBED + o];
    }
    __syncthreads();
    int i2 = blockIdx.y * 32 + tx;
#pragma unroll
    for (int r = 0; r < 4; r++) {
        int o2 = blockIdx.x * 32 + ty + r * 8;
        Wt[(size_t)o2 * EMBED + i2] = f2bf(tile[tx][ty + r * 8]);
    }
}

// ---------------- GEMM: C[M][N] = A[M][K] * B[N][K]^T  (bf16 in, fp32 acc) --
template<int MODE>
__global__ __launch_bounds__(256)
void gemm_kernel(const unsigned short* __restrict__ A,
                 const unsigned short* __restrict__ B,
                 int K,
                 unsigned short* __restrict__ Qo,
                 unsigned short* __restrict__ Ko,
                 unsigned short* __restrict__ Vto,
                 const float* __restrict__ bq,
                 const float* __restrict__ bk,
                 const float* __restrict__ bvv,
                 float* __restrict__ Co,
                 const float* __restrict__ bo) {
    __shared__ __attribute__((aligned(16))) unsigned short As[128 * 64];
    __shared__ __attribute__((aligned(16))) unsigned short Bs[128 * 64];
    const int t = threadIdx.x;
    const int lane = t & 63;
    const int w = t >> 6;
    const int wr = w >> 1, wc = w & 1;
    const int l15 = lane & 15, l16 = lane >> 4;
    const int m0 = blockIdx.y * 128;
    const int n0 = blockIdx.x * 128;

    f32x4 acc[4][4];
#pragma unroll
    for (int i = 0; i < 4; i++)
#pragma unroll
        for (int j = 0; j < 4; j++) acc[i][j] = (f32x4){0.f, 0.f, 0.f, 0.f};

    for (int k0 = 0; k0 < K; k0 += 64) {
        __syncthreads();
#pragma unroll
        for (int i = 0; i < 4; i++) {
            int c = i * 256 + t;
            int row = c >> 3;
            int lc = (c & 7) ^ (row & 7);
            g2l16(A + (size_t)(m0 + row) * K + k0 + lc * 8,
                  As + (size_t)(i * 256 + (t & ~63)) * 8);
        }
#pragma unroll
        for (int i = 0; i < 4; i++) {
            int c = i * 256 + t;
            int row = c >> 3;
            int lc = (c & 7) ^ (row & 7);
            g2l16(B + (size_t)(n0 + row) * K + k0 + lc * 8,
                  Bs + (size_t)(i * 256 + (t & ~63)) * 8);
        }
        __syncthreads();
#pragma unroll
        for (int kk = 0; kk < 2; kk++) {
            short8 a[4], b[4];
#pragma unroll
            for (int ai = 0; ai < 4; ai++) {
                int row = wr * 64 + ai * 16 + l15;
                int ch = kk * 4 + l16;
                a[ai] = *reinterpret_cast<const short8*>(
                    As + row * 64 + ((ch ^ (row & 7)) << 3));
            }
#pragma unroll
            for (int bj = 0; bj < 4; bj++) {
                int row = wc * 64 + bj * 16 + l15;
                int ch = kk * 4 + l16;
                b[bj] = *reinterpret_cast<const short8*>(
                    Bs + row * 64 + ((ch ^ (row & 7)) << 3));
            }
#pragma unroll
            for (int ai = 0; ai < 4; ai++)
#pragma unroll
                for (int bj = 0; bj < 4; bj++)
                    acc[ai][bj] = __builtin_amdgcn_mfma_f32_16x16x32_bf16(
                        a[ai], b[bj], acc[ai][bj], 0, 0, 0);
        }
    }

    if (MODE == 0) {
        const int which = n0 >> 10;        // 0=Q 1=K 2=V
        const int coln = n0 & 1023;
        const float* bias = which == 0 ? bq : (which == 1 ? bk : bvv);
        // Q pre-scaled by softmax scale * LOG2E (softmax done in log2 domain)
        const float scale = which == 0 ? 0.125f * LOG2E : 1.0f;
#pragma unroll
        for (int ai = 0; ai < 4; ai++) {
            int rowb = m0 + wr * 64 + ai * 16 + l16 * 4;
            int b_ = rowb >> 11;
            int s = rowb & 2047;
#pragma unroll
            for (int bj = 0; bj < 4; bj++) {
                int col = coln + wc * 64 + bj * 16 + l15;
                float bsv = bias[col];
                int h = col >> 6, d = col & 63;
                if (which < 2) {
                    unsigned short* dst = (which == 0) ? Qo : Ko;
                    size_t base = ((size_t)(b_ * HEADS + h)) * SEQ * HDIM;
#pragma unroll
                    for (int r = 0; r < 4; r++) {
                        float v = (acc[ai][bj][r] + bsv) * scale;
                        dst[base + (size_t)(s + r) * HDIM + d] = f2bf(v);
                    }
                } else {
                    ushort4 pk;
                    pk.x = f2bf(acc[ai][bj][0] + bsv);
                    pk.y = f2bf(acc[ai][bj][1] + bsv);
                    pk.z = f2bf(acc[ai][bj][2] + bsv);
                    pk.w = f2bf(acc[ai][bj][3] + bsv);
                    size_t off = ((size_t)(b_ * HEADS + h) * HDIM + d) * SEQ + s;
                    *reinterpret_cast<ushort4*>(Vto + off) = pk;
                }
            }
        }
    } else {
#pragma unroll
        for (int ai = 0; ai < 4; ai++) {
            int rowb = m0 + wr * 64 + ai * 16 + l16 * 4;
#pragma unroll
            for (int bj = 0; bj < 4; bj++) {
                int col = n0 + wc * 64 + bj * 16 + l15;
                float bsv = bo[col];
#pragma unroll
                for (int r = 0; r < 4; r++)
                    Co[(size_t)(rowb + r) * EMBED + col] = acc[ai][bj][r] + bsv;
            }
        }
    }
}

// ---------------- causal flash attention (swapped-QK^T, in-reg softmax) -----
// Q,K: [bh][s][64] bf16 (Q pre-scaled by 0.125*LOG2E); V: [bh][64][s] bf16.
// O: [b*s][1024] bf16. 4 waves x 32 q-rows = 128 q-rows/block; KV tile 64;
// K/V double-buffered in LDS; Q fragments loaded directly from global.
__device__ __forceinline__ void stage_kv(const unsigned short* __restrict__ Kg,
                                         const unsigned short* __restrict__ Vg,
                                         int kv0, unsigned short* Ksb,
                                         unsigned short* Vsb, int t) {
#pragma unroll
    for (int i = 0; i < 2; i++) {          // K tile [64 keys][64 d]
        int c = i * 256 + t;
        int row = c >> 3;
        int lc = (c & 7) ^ (row & 7);
        g2l16(Kg + (size_t)(kv0 + row) * HDIM + lc * 8,
              Ksb + (i * 256 + (t & ~63)) * 8);
    }
#pragma unroll
    for (int i = 0; i < 2; i++) {          // V^T tile [64 d][64 keys]
        int c = i * 256 + t;
        int d = c >> 3;
        int lc = (c & 7) ^ (d & 7);
        g2l16(Vg + (size_t)d * SEQ + kv0 + lc * 8,
              Vsb + (i * 256 + (t & ~63)) * 8);
    }
}

__global__ __launch_bounds__(256, 3)
void attn_kernel(const unsigned short* __restrict__ Q,
                 const unsigned short* __restrict__ Kk,
                 const unsigned short* __restrict__ Vt,
                 unsigned short* __restrict__ O) {
    __shared__ __attribute__((aligned(16))) unsigned short Ks[2][64 * 64];
    __shared__ __attribute__((aligned(16))) unsigned short Vs[2][64 * 64];
    __shared__ __attribute__((aligned(16))) unsigned short Ps[4][32 * 64];

    const int t = threadIdx.x;
    const int lane = t & 63;
    const int w = t >> 6;
    const int l15 = lane & 15, l16 = lane >> 4;
    const int bh = blockIdx.y;
    const int q0 = blockIdx.x * 128;
    const size_t base = (size_t)bh * SEQ * HDIM;
    const unsigned short* Kg = Kk + base;
    const unsigned short* Vg = Vt + base;
    const int qrow0 = q0 + w * 32;

    // Q fragments (B-operand): lane holds Q[qb*16+l15][(kc*4+l16)*8 .. +8]
    short8 qf[2][2];
    {
        const unsigned short* Qg = Q + base + (size_t)qrow0 * HDIM;
#pragma unroll
        for (int qb = 0; qb < 2; qb++)
#pragma unroll
            for (int kc = 0; kc < 2; kc++)
                qf[qb][kc] = *reinterpret_cast<const short8*>(
                    Qg + (qb * 16 + l15) * HDIM + (kc * 4 + l16) * 8);
    }

    f32x4 oacc[2][4];
#pragma unroll
    for (int qb = 0; qb < 2; qb++)
#pragma unroll
        for (int nd = 0; nd < 4; nd++) oacc[qb][nd] = (f32x4){0.f, 0.f, 0.f, 0.f};
    float m_run[2] = {-1e30f, -1e30f};
    float l_run[2] = {0.f, 0.f};

    const int ntiles = (q0 >> 6) + 2;

    stage_kv(Kg, Vg, 0, Ks[0], Vs[0], t);
    __syncthreads();

    for (int tk = 0; tk < ntiles; tk++) {
        const int kv0 = tk * 64;
        const int cur = tk & 1;
        if (tk + 1 < ntiles)
            stage_kv(Kg, Vg, kv0 + 64, Ks[cur ^ 1], Vs[cur ^ 1], t);

        if (kv0 <= qrow0 + 31) {
            const unsigned short* Kb = Ks[cur];
            const unsigned short* Vb = Vs[cur];
            // ---- S^T = K * Q^T : rows = keys, cols = q
            f32x4 sc[2][4];
#pragma unroll
            for (int qb = 0; qb < 2; qb++)
#pragma unroll
                for (int kb = 0; kb < 4; kb++) sc[qb][kb] = (f32x4){0.f, 0.f, 0.f, 0.f};
#pragma unroll
            for (int kc = 0; kc < 2; kc++) {
                short8 ka[4];
#pragma unroll
                for (int kb = 0; kb < 4; kb++) {
                    int row = kb * 16 + l15;
                    ka[kb] = *reinterpret_cast<const short8*>(
                        Kb + row * 64 + (((kc * 4 + l16) ^ (row & 7)) << 3));
                }
#pragma unroll
                for (int qb = 0; qb < 2; qb++)
#pragma unroll
                    for (int kb = 0; kb < 4; kb++)
                        sc[qb][kb] = __builtin_amdgcn_mfma_f32_16x16x32_bf16(
                            ka[kb], qf[qb][kc], sc[qb][kb], 0, 0, 0);
            }
            // ---- causal mask (diagonal tiles only)
            if (kv0 + 63 > qrow0) {
#pragma unroll
                for (int qb = 0; qb < 2; qb++) {
                    int q = qrow0 + qb * 16 + l15;
#pragma unroll
                    for (int kb = 0; kb < 4; kb++)
#pragma unroll
                        for (int r = 0; r < 4; r++) {
                            int k = kv0 + kb * 16 + l16 * 4 + r;
                            sc[qb][kb][r] = (k > q) ? -1e30f : sc[qb][kb][r];
                        }
                }
            }
            // ---- row max (in-register + 2 shuffles), defer-rescale vote
            float vmax[2];
            bool need = false;
#pragma unroll
            for (int qb = 0; qb < 2; qb++) {
                float mx = -1e30f;
#pragma unroll
                for (int kb = 0; kb < 4; kb++) {
                    float a = fmaxf(fmaxf(sc[qb][kb][0], sc[qb][kb][1]),
                                    fmaxf(sc[qb][kb][2], sc[qb][kb][3]));
                    mx = fmaxf(mx, a);
                }
                mx = fmaxf(mx, __shfl_xor(mx, 16));
                mx = fmaxf(mx, __shfl_xor(mx, 32));
                vmax[qb] = mx;
                need = need || (mx > m_run[qb] + 8.0f);
            }
            if (__any(need)) {
#pragma unroll
                for (int qb = 0; qb < 2; qb++) {
                    float mn = fmaxf(m_run[qb], vmax[qb]);
                    float sf = __builtin_amdgcn_exp2f(m_run[qb] - mn);
                    m_run[qb] = mn;
                    l_run[qb] *= sf;
#pragma unroll
                    for (int r = 0; r < 4; r++) {
                        float sfr = __shfl(sf, l16 * 4 + r);
#pragma unroll
                        for (int nd = 0; nd < 4; nd++) oacc[qb][nd][r] *= sfr;
                    }
                }
            }
            // ---- P = exp2(S - m), row-sum, packed swizzled LDS write
#pragma unroll
            for (int qb = 0; qb < 2; qb++) {
                const int row = qb * 16 + l15;
                const int rx = (row & 7) << 3;
                float ps = 0.f;
#pragma unroll
                for (int kb = 0; kb < 4; kb++) {
                    float p0 = __builtin_amdgcn_exp2f(sc[qb][kb][0] - m_run[qb]);
                    float p1 = __builtin_amdgcn_exp2f(sc[qb][kb][1] - m_run[qb]);
                    float p2 = __builtin_amdgcn_exp2f(sc[qb][kb][2] - m_run[qb]);
                    float p3 = __builtin_amdgcn_exp2f(sc[qb][kb][3] - m_run[qb]);
                    ps += (p0 + p1) + (p2 + p3);
                    unsigned int lo = (unsigned int)f2bf(p0) |
                                      ((unsigned int)f2bf(p1) << 16);
                    unsigned int hi = (unsigned int)f2bf(p2) |
                                      ((unsigned int)f2bf(p3) << 16);
                    int kel = (kb * 16 + l16 * 4) ^ rx;
                    *reinterpret_cast<unsigned int*>(&Ps[w][row * 64 + kel]) = lo;
                    *reinterpret_cast<unsigned int*>(&Ps[w][row * 64 + kel + 2]) = hi;
                }
                ps += __shfl_xor(ps, 16);
                ps += __shfl_xor(ps, 32);
                l_run[qb] += ps;
            }
            // ---- PV: oacc += P[32 x 64k] * V^T[64d x 64k]^T
#pragma unroll
            for (int kc = 0; kc < 2; kc++) {
                short8 vb[4], pa[2];
#pragma unroll
                for (int nd = 0; nd < 4; nd++) {
                    int row = nd * 16 + l15;
                    vb[nd] = *reinterpret_cast<const short8*>(
                        Vb + row * 64 + (((kc * 4 + l16) ^ (row & 7)) << 3));
                }
#pragma unroll
                for (int qb = 0; qb < 2; qb++) {
                    int row = qb * 16 + l15;
                    pa[qb] = *reinterpret_cast<const short8*>(
                        &Ps[w][row * 64 + (((kc * 4 + l16) ^ (row & 7)) << 3)]);
                }
#pragma unroll
                for (int qb = 0; qb < 2; qb++)
#pragma unroll
                    for (int nd = 0; nd < 4; nd++)
                        oacc[qb][nd] = __builtin_amdgcn_mfma_f32_16x16x32_bf16(
                            pa[qb], vb[nd], oacc[qb][nd], 0, 0, 0);
            }
        }
        __syncthreads();
    }

    // ---- finalize
    const int b_ = bh >> 4, h = bh & 15;
#pragma unroll
    for (int qb = 0; qb < 2; qb++) {
        float li = 1.0f / l_run[qb];
#pragma unroll
        for (int r = 0; r < 4; r++) {
            float lir = __shfl(li, l16 * 4 + r);
            int row = b_ * SEQ + q0 + w * 32 + qb * 16 + l16 * 4 + r;
#pragma unroll
            for (int nd = 0; nd < 4; nd++)
                O[(size_t)row * EMBED + h * 64 + nd * 16 + l15] =
                    f2bf(oacc[qb][nd][r] * lir);
        }
    }
}

extern "C" void kernel_launch(void* const* d_in, const int* in_sizes, int n_in,
                              void* d_out, int out_size, void* d_ws, size_t ws_size,
                              hipStream_t stream) {
    (void)in_sizes; (void)n_in; (void)out_size; (void)ws_size;
    const float* x  = (const float*)d_in[0];
    const float* Wq = (const float*)d_in[1];
    const float* bq = (const float*)d_in[2];
    const float* Wk = (const float*)d_in[3];
    const float* bk = (const float*)d_in[4];
    const float* Wv = (const float*)d_in[5];
    const float* bv = (const float*)d_in[6];
    const float* Wo = (const float*)d_in[7];
    const float* bo = (const float*)d_in[8];
    float* out = (float*)d_out;

    unsigned short* xb   = (unsigned short*)d_ws;
    unsigned short* Wqkv = xb + (size_t)NROWS * EMBED;          // [3][1024][1024]
    unsigned short* Wot  = Wqkv + (size_t)3 * EMBED * EMBED;
    unsigned short* Qb   = Wot + (size_t)EMBED * EMBED;         // [b,h,s,d]
    unsigned short* Kb   = Qb + (size_t)NROWS * EMBED;
    unsigned short* Vtb  = Kb + (size_t)NROWS * EMBED;          // [b,h,d,s]
    unsigned short* attn = Vtb + (size_t)NROWS * EMBED;         // [b*s][1024]

    cast_x_kernel<<<(NROWS * EMBED / 4 + 255) / 256, 256, 0, stream>>>(
        x, xb, NROWS * EMBED / 4);
    dim3 tgrid(32, 32), tblk(32, 8);
    transW_kernel<<<tgrid, tblk, 0, stream>>>(Wq, Wqkv);
    transW_kernel<<<tgrid, tblk, 0, stream>>>(Wk, Wqkv + (size_t)EMBED * EMBED);
    transW_kernel<<<tgrid, tblk, 0, stream>>>(Wv, Wqkv + (size_t)2 * EMBED * EMBED);
    transW_kernel<<<tgrid, tblk, 0, stream>>>(Wo, Wot);

    gemm_kernel<0><<<dim3(24, 32), 256, 0, stream>>>(
        xb, Wqkv, EMBED, Qb, Kb, Vtb, bq, bk, bv, nullptr, nullptr);

    attn_kernel<<<dim3(SEQ / 128, BATCH * HEADS), 256, 0, stream>>>(
        Qb, Kb, Vtb, attn);

    gemm_kernel<1><<<dim3(8, 32), 256, 0, stream>>>(
        attn, Wot, EMBED, nullptr, nullptr, nullptr, nullptr, nullptr, nullptr,
        out, bo);
}